// Round 11
// baseline (3685.977 us; speedup 1.0000x reference)
//
#include <hip/hip_runtime.h>
#include <hip/hip_bf16.h>

// ---------------- problem dims ----------------
#define TT 40
#define BB 64
#define LL 80
#define DD 256
#define HH 1024
#define G4H 4096
#define AA 18
#define KENC 1280   // [demo(256) | h(1024)]
#define KLSTM 2048  // [x(1024) | h(1024)]
#define KCOMB 1280  // [attn(1024) | obs(256)]
#define QSZ (TT*BB*AA)

#define GROUPS 8    // independent batch groups
#define GBLK 64     // blocks per group (sync participants)
#define NBLK (GROUPS*GBLK)   // 512 blocks, 2 per CU
#define NSLOT_E (LL+1)
#define NSLOT_D (TT+1)
#define FLAG_STRIDE 16       // dwords -> 64B per flag

typedef __bf16 bf16x8 __attribute__((ext_vector_type(8)));
typedef float  f32x4  __attribute__((ext_vector_type(4)));

// ---------------- workspace layout (bytes) ----------------
#define OFF_WENC   ((size_t)0)
#define OFF_WLSTM  (OFF_WENC  + (size_t)G4H*KENC*2)
#define OFF_WCOMB  (OFF_WLSTM + (size_t)G4H*KLSTM*2)
#define OFF_WMID   (OFF_WCOMB + (size_t)HH*KCOMB*2)
#define OFF_BIASE  (OFF_WMID  + (size_t)HH*HH*2)
#define OFF_BIASL  (OFF_BIASE + (size_t)G4H*4)
#define OFF_DEMO   (OFF_BIASL + (size_t)G4H*4)
#define OFF_STATE  (OFF_DEMO  + (size_t)BB*LL*DD*2)
#define OFF_ENC    (OFF_STATE + (size_t)TT*BB*DD*2)
#define OFF_HDEC   (OFF_ENC   + (size_t)BB*LL*HH*2)
#define OFF_XALL   (OFF_HDEC  + (size_t)TT*BB*HH*2)
#define OFF_MF     (OFF_XALL  + (size_t)TT*BB*HH*2)
#define OFF_ATTNS  (OFF_MF    + (size_t)TT*BB*HH*2)
#define OFF_HROT   (OFF_ATTNS + (size_t)BB*HH*2)
#define OFF_BAR    (OFF_HROT  + (size_t)GROUPS*(NSLOT_E+NSLOT_D)*8*HH*2)

// ---------------- helpers ----------------
__device__ __forceinline__ float sigm(float x){ return 1.f/(1.f+__expf(-x)); }

__device__ __forceinline__ float wred_sum(float v){
#pragma unroll
  for (int s=32; s>0; s>>=1) v += __shfl_xor(v, s, 64);
  return v;
}
__device__ __forceinline__ float wred_max(float v){
#pragma unroll
  for (int s=32; s>0; s>>=1) v = fmaxf(v, __shfl_xor(v, s, 64));
  return v;
}

// write-through (coherent) 2B store: visible at MALL, no stale L2 copies
__device__ __forceinline__ void st_b16_sc(__bf16* p, float v){
  unsigned short u = __builtin_bit_cast(unsigned short, (__bf16)v);
  asm volatile("global_store_short %0, %1, off sc0 sc1"
               :: "v"(p), "v"((unsigned)u) : "memory");
}

// 64-participant group barrier: per-block flag + 64-lane poll
__device__ __forceinline__ void grp_arrive(unsigned* flags, unsigned target, int bk){
  __syncthreads();   // all waves' stores drained (vmcnt0) before flag
  if (threadIdx.x == 0) {
    __builtin_amdgcn_fence(__ATOMIC_RELEASE, "agent");
    __hip_atomic_store(flags + (size_t)bk*FLAG_STRIDE, target,
                       __ATOMIC_RELAXED, __HIP_MEMORY_SCOPE_AGENT);
  }
}
__device__ __forceinline__ void grp_wait(unsigned* flags, unsigned target, int g){
  if (threadIdx.x < 64) {
    unsigned long long spins = 0;
    for (;;) {
      unsigned a = __hip_atomic_load(flags + (size_t)(g*GBLK + threadIdx.x)*FLAG_STRIDE,
                                     __ATOMIC_RELAXED, __HIP_MEMORY_SCOPE_AGENT);
      if (__all((int)(a >= target))) break;
      if (++spins > (1ull<<20)) break;   // fail loud, never hang
      __builtin_amdgcn_s_sleep(1);
    }
  }
  __syncthreads();
  asm volatile("" ::: "memory");
}

// ---------------- fused prologue (one dispatch) ----------------
// [0,4096) pack enc | [4096,8192) pack lstm | [8192,13312) comb
// [13312,17408) mid | [17408,22528) demo | [22528,25088) state
// [25088,25216) zero enc h slot0 | [25216,25280) zero flags
#define PB1 4096
#define PB2 8192
#define PB3 13312
#define PB4 17408
#define PB5 22528
#define PB6 25088
#define PB7 25216
#define PGRID 25280
__global__ __launch_bounds__(256)
void k_prep(const float* __restrict__ enc_wih, const float* __restrict__ enc_whh,
            const float* __restrict__ enc_bih, const float* __restrict__ enc_bhh,
            const float* __restrict__ lstm_wih, const float* __restrict__ lstm_whh,
            const float* __restrict__ lstm_bih, const float* __restrict__ lstm_bhh,
            const float* __restrict__ comb_w, const float* __restrict__ mid_w,
            const float* __restrict__ demo, const float* __restrict__ state,
            char* __restrict__ ws){
  int blk = blockIdx.x, tid = threadIdx.x;
  if (blk < PB1) {                    // pack enc gate rows (p = col*4 + gate interleave)
    int p = blk;
    int gate = p & 3, jj = (p >> 2) & 3, bq = p >> 4;
    int orig = gate*HH + bq*4 + jj;
    if (tid == 0) ((float*)(ws + OFF_BIASE))[p] = enc_bih[orig] + enc_bhh[orig];
    const float* s0 = enc_wih + (size_t)orig*DD;
    const float* s1 = enc_whh + (size_t)orig*HH;
    __bf16* d = (__bf16*)(ws + OFF_WENC) + (size_t)p*KENC;
    for (int k = tid; k < KENC; k += 256)
      d[k] = (__bf16)(k < DD ? s0[k] : s1[k-DD]);
  } else if (blk < PB2) {             // pack lstm gate rows
    int p = blk - PB1;
    int gate = p & 3, jj = (p >> 2) & 3, bq = p >> 4;
    int orig = gate*HH + bq*4 + jj;
    if (tid == 0) ((float*)(ws + OFF_BIASL))[p] = lstm_bih[orig] + lstm_bhh[orig];
    const float* s0 = lstm_wih + (size_t)orig*HH;
    const float* s1 = lstm_whh + (size_t)orig*HH;
    __bf16* d = (__bf16*)(ws + OFF_WLSTM) + (size_t)p*KLSTM;
    for (int k = tid; k < KLSTM; k += 256)
      d[k] = (__bf16)(k < HH ? s0[k] : s1[k-HH]);
  } else if (blk < PB3) {             // comb
    int i = (blk - PB2)*256 + tid;
    ((__bf16*)(ws + OFF_WCOMB))[i] = (__bf16)comb_w[i];
  } else if (blk < PB4) {             // mid
    int i = (blk - PB3)*256 + tid;
    ((__bf16*)(ws + OFF_WMID))[i] = (__bf16)mid_w[i];
  } else if (blk < PB5) {             // demo  [B][L][D]
    int i = (blk - PB4)*256 + tid;
    ((__bf16*)(ws + OFF_DEMO))[i] = (__bf16)demo[i];
  } else if (blk < PB6) {             // state [T][B][D]
    int i = (blk - PB5)*256 + tid;
    ((__bf16*)(ws + OFF_STATE))[i] = (__bf16)state[i];
  } else if (blk < PB7) {             // zero enc h slot0, all groups
    int i = (blk - PB6)*256 + tid;    // dword index, 4096 dwords per group slot0
    int g = i >> 12, r = i & 4095;
    ((unsigned*)(ws + OFF_HROT))[(size_t)g*(NSLOT_E*8*HH/2) + r] = 0u;
  } else {                            // zero both flag arrays (16384 dwords)
    int i = (blk - PB7)*256 + tid;
    ((unsigned*)(ws + OFF_BAR))[i] = 0u;
  }
}

// ---------------- encoder: 8 independent groups, 64-block sync each ---------
// block bk -> (g = bk>>6, b64 = bk&63). Block owns gates [b64*64, +64) =
// h-cols [b64*16, +16) for group g's 8 batches. 4 waves x 16 gates, full K.
__global__ __launch_bounds__(256, 2)
void k_enc(const __bf16* __restrict__ demoC, const __bf16* __restrict__ wEnc,
           const float* __restrict__ bE, __bf16* __restrict__ hrotE,
           __bf16* __restrict__ encB, unsigned* __restrict__ flagsE){
  const int bk = blockIdx.x, tid = threadIdx.x;
  const int g = bk >> 6, b64 = bk & 63;
  const int wv = tid >> 6, ln = tid & 63;
  const int l15 = ln & 15, lhi = ln >> 4;
  const int klane = lhi * 8;
  const int mb = l15 & 7;                       // A-row batch (dup for l15>=8)
  const int batch = g*8 + mb;

  __shared__ float g_lds[8][68];

  const __bf16* brow = wEnc + (size_t)(b64*64 + wv*16 + l15)*KENC;
  const __bf16* drow = demoC + (size_t)batch*LL*DD;
  __bf16* hbase = hrotE + (size_t)g*NSLOT_E*8*HH;

  const int em = tid >> 4, ec = tid & 15;       // elementwise: batch, col16
  const int ecol = b64*16 + ec;
  const int ebatch = g*8 + em;
  float creg = 0.f;

  for (int t = 0; t < LL; ++t) {
    const __bf16* hR = hbase + (size_t)t*8*HH + (size_t)mb*HH;
    const __bf16* arow = drow + (size_t)t*DD;
    f32x4 acc = {0.f,0.f,0.f,0.f};
#pragma unroll 8
    for (int kk = 0; kk < KENC; kk += 32) {
      int k0 = kk + klane;
      const __bf16* pa = (k0 < DD) ? (arow + k0) : (hR + (k0 - DD));
      acc = __builtin_amdgcn_mfma_f32_16x16x32_bf16(*(const bf16x8*)pa,
                                                    *(const bf16x8*)(brow + k0), acc, 0,0,0);
    }
    {
      int r0 = lhi*4;
#pragma unroll
      for (int r = 0; r < 4; ++r) {
        int row = r0 + r;
        if (row < 8) g_lds[row][wv*16 + l15] = acc[r];   // rows 8-15 = dup batches, dropped
      }
    }
    __syncthreads();
    if (tid < 128) {
      int pb = b64*64 + ec*4;
      float gi = g_lds[em][ec*4+0] + bE[pb+0];
      float gf = g_lds[em][ec*4+1] + bE[pb+1];
      float gg = g_lds[em][ec*4+2] + bE[pb+2];
      float go = g_lds[em][ec*4+3] + bE[pb+3];
      creg = sigm(gf)*creg + sigm(gi)*tanhf(gg);
      float hn = sigm(go)*tanhf(creg);
      st_b16_sc(hbase + (size_t)(t+1)*8*HH + (size_t)em*HH + ecol, hn);
      encB[((size_t)ebatch*LL + t)*HH + ecol] = (__bf16)hn;   // read next dispatch
    }
    grp_arrive(flagsE, (unsigned)(t+1), bk);
    grp_wait(flagsE, (unsigned)(t+1), g);
  }
}

// ---------------- decoder: same grouping, K=2048 ----------------
__global__ __launch_bounds__(256, 2)
void k_dec(const __bf16* __restrict__ xall, const __bf16* __restrict__ wLstm,
           const float* __restrict__ bL, const float* __restrict__ c0,
           __bf16* __restrict__ hrotD, __bf16* __restrict__ hdec,
           float* __restrict__ out, unsigned* __restrict__ flagsD){
  const int bk = blockIdx.x, tid = threadIdx.x;
  const int g = bk >> 6, b64 = bk & 63;
  const int wv = tid >> 6, ln = tid & 63;
  const int l15 = ln & 15, lhi = ln >> 4;
  const int klane = lhi * 8;
  const int mb = l15 & 7;
  const int batch = g*8 + mb;

  __shared__ float g_lds[8][68];

  const __bf16* brow = wLstm + (size_t)(b64*64 + wv*16 + l15)*KLSTM;
  __bf16* hbase = hrotD + (size_t)g*NSLOT_D*8*HH;

  const int em = tid >> 4, ec = tid & 15;
  const int ecol = b64*16 + ec;
  const int ebatch = g*8 + em;
  float creg = (tid < 128) ? c0[(size_t)ebatch*HH + ecol] : 0.f;

  for (int t = 0; t < TT; ++t) {
    const __bf16* hR = hbase + (size_t)t*8*HH + (size_t)mb*HH;
    const __bf16* xrow = xall + ((size_t)t*BB + batch)*HH;
    f32x4 acc = {0.f,0.f,0.f,0.f};
#pragma unroll 8
    for (int kk = 0; kk < KLSTM; kk += 32) {
      int k0 = kk + klane;
      const __bf16* pa = (k0 < HH) ? (xrow + k0) : (hR + (k0 - HH));
      acc = __builtin_amdgcn_mfma_f32_16x16x32_bf16(*(const bf16x8*)pa,
                                                    *(const bf16x8*)(brow + k0), acc, 0,0,0);
    }
    {
      int r0 = lhi*4;
#pragma unroll
      for (int r = 0; r < 4; ++r) {
        int row = r0 + r;
        if (row < 8) g_lds[row][wv*16 + l15] = acc[r];
      }
    }
    __syncthreads();
    if (tid < 128) {
      int pb = b64*64 + ec*4;
      float gi = g_lds[em][ec*4+0] + bL[pb+0];
      float gf = g_lds[em][ec*4+1] + bL[pb+1];
      float gg = g_lds[em][ec*4+2] + bL[pb+2];
      float go = g_lds[em][ec*4+3] + bL[pb+3];
      creg = sigm(gf)*creg + sigm(gi)*tanhf(gg);
      float hn = sigm(go)*tanhf(creg);
      st_b16_sc(hbase + (size_t)(t+1)*8*HH + (size_t)em*HH + ecol, hn);
      hdec[((size_t)t*BB + ebatch)*HH + ecol] = (__bf16)hn;   // read next dispatch
      if (t == TT-1) out[QSZ + (size_t)ebatch*HH + ecol] = hn;  // exact fp32
    }
    grp_arrive(flagsD, (unsigned)(t+1), bk);
    grp_wait(flagsD, (unsigned)(t+1), g);
  }
  if (tid < 128) out[QSZ + BB*HH + (size_t)ebatch*HH + ecol] = creg;  // exact fp32 c
}

// ---------------- static attention + decoder h slot0 init ----------------
// softmax is h-independent: scores = score_d[b,l] + (h.Wh)[b] -> per-row
// constant shift cancels. Attn weights shared across all decoder t.
__global__ __launch_bounds__(256)
void k_attn(const int* __restrict__ demlen, const float* __restrict__ h0,
            const float* __restrict__ attn_w, const __bf16* __restrict__ encB,
            __bf16* __restrict__ attnS, __bf16* __restrict__ hrotD){
  const int bk = blockIdx.x, tid = threadIdx.x;
  const int wv = tid >> 6, ln = tid & 63;
  __shared__ float sc_sh[LL];
  __shared__ float w_sh[LL];
  int b = bk >> 2, qq = bk & 3;
  for (int i = 0; i < 20; ++i) {
    int l = wv*20 + i;
    const __bf16* er = encB + ((size_t)b*LL + l)*HH + ln*16;
    bf16x8 e0 = *(const bf16x8*)(er);
    bf16x8 e1 = *(const bf16x8*)(er + 8);
    float part = 0.f;
#pragma unroll
    for (int j = 0; j < 8; ++j) {
      part += (float)e0[j] * attn_w[ln*16 + j];
      part += (float)e1[j] * attn_w[ln*16 + 8 + j];
    }
    part = wred_sum(part);
    if (ln == 0) sc_sh[l] = part;
  }
  __syncthreads();
  if (wv == 0) {
    int len = demlen[b];
    float s0 = (ln < len) ? sc_sh[ln] : -1e30f;
    float s1 = (ln < 16 && 64+ln < len) ? sc_sh[64+ln] : -1e30f;
    float mx = wred_max(fmaxf(s0, s1));
    float e0 = __expf(s0 - mx);
    float e1 = (ln < 16) ? __expf(s1 - mx) : 0.f;
    float inv = 1.f / wred_sum(e0 + e1);
    w_sh[ln] = e0 * inv;
    if (ln < 16) w_sh[64+ln] = e1 * inv;
  }
  __syncthreads();
  {
    int col = qq*256 + tid;
    float a = 0.f;
    const __bf16* eb = encB + (size_t)b*LL*HH + col;
#pragma unroll 4
    for (int l = 0; l < LL; ++l) a += w_sh[l] * (float)eb[(size_t)l*HH];
    attnS[(size_t)b*HH + col] = (__bf16)a;
  }
  // dec h slot0 = h0 (grouped layout), grid-stride
  for (int i = bk*256 + tid; i < BB*HH; i += 256*256) {
    int bb2 = i >> 10, col = i & 1023;
    int gg2 = bb2 >> 3, mm2 = bb2 & 7;
    hrotD[((size_t)gg2*NSLOT_D*8 + mm2)*HH + col] = (__bf16)h0[i];
  }
}

// ---------------- phase X: x_all = relu([attn|obs_t] @ combW^T + b) --------
__global__ __launch_bounds__(256)
void k_x(const __bf16* __restrict__ attnS, const __bf16* __restrict__ stateB,
         const __bf16* __restrict__ wComb, const float* __restrict__ comb_b,
         __bf16* __restrict__ xall){
  const int bk = blockIdx.x, tid = threadIdx.x;
  const int wv = tid >> 6, ln = tid & 63;
  const int l15 = ln & 15, lhi = ln >> 4;
  const int klane = lhi * 8;
  int g = bk*4 + wv;
  for (int i = 0; i < 10; ++i) {
    int ti = i*1024 + g;
    int mtt = ti >> 6, nt = ti & 63;
    f32x4 acc = {0.f,0.f,0.f,0.f};
    const __bf16* brow = wComb + (size_t)(nt*16 + l15)*KCOMB;
    int r = mtt*16 + l15, bb = r & 63;
    const __bf16* aat = attnS + (size_t)bb*HH;
    const __bf16* ast = stateB + (size_t)r*DD;
#pragma unroll 8
    for (int kk = 0; kk < KCOMB; kk += 32) {
      int k0 = kk + klane;
      bf16x8 af = (k0 < HH) ? *(const bf16x8*)(aat + k0)
                            : *(const bf16x8*)(ast + (k0-HH));
      acc = __builtin_amdgcn_mfma_f32_16x16x32_bf16(af, *(const bf16x8*)(brow + k0), acc, 0,0,0);
    }
    int col = nt*16 + l15;
    float cb = comb_b[col];
    int r0 = mtt*16 + lhi*4;
#pragma unroll
    for (int rr = 0; rr < 4; ++rr)
      xall[(size_t)(r0+rr)*HH + col] = (__bf16)fmaxf(acc[rr]+cb, 0.f);
  }
}

// ---------------- epilogue: m = hdec @ midW^T + mid_b ----------------
__global__ __launch_bounds__(256)
void k_mid(const __bf16* __restrict__ hdec, const __bf16* __restrict__ wMid,
           const float* __restrict__ mid_b, __bf16* __restrict__ mf){
  const int bk = blockIdx.x, tid = threadIdx.x;
  const int wv = tid >> 6, ln = tid & 63;
  const int l15 = ln & 15, lhi = ln >> 4;
  const int klane = lhi * 8;
  int g = bk*4 + wv;
  for (int i = 0; i < 10; ++i) {
    int ti = i*1024 + g;
    int mtt = ti >> 6, nt = ti & 63;
    f32x4 acc = {0.f,0.f,0.f,0.f};
    const __bf16* brow = wMid + (size_t)(nt*16 + l15)*HH;
    const __bf16* arow = hdec + (size_t)(mtt*16 + l15)*HH;
#pragma unroll 8
    for (int kk = 0; kk < HH; kk += 32) {
      int k0 = kk + klane;
      acc = __builtin_amdgcn_mfma_f32_16x16x32_bf16(*(const bf16x8*)(arow + k0),
                                                    *(const bf16x8*)(brow + k0), acc, 0,0,0);
    }
    int col = nt*16 + l15;
    float mb = mid_b[col];
    int r0 = mtt*16 + lhi*4;
#pragma unroll
    for (int rr = 0; rr < 4; ++rr)
      mf[(size_t)(r0+rr)*HH + col] = (__bf16)(acc[rr]+mb);
  }
}

// ---------------- q = mf @ outW^T + out_b ----------------
__global__ __launch_bounds__(256)
void k_out(const __bf16* __restrict__ mf, const float* __restrict__ out_w,
           const float* __restrict__ out_b, float* __restrict__ out){
  const int bk = blockIdx.x, tid = threadIdx.x;
  const int wv = tid >> 6, ln = tid & 63;
  int g = bk*4 + wv;
  for (int i = 0; i < 3; ++i) {
    int row = i*1024 + g;
    if (row < TT*BB) {
      const __bf16* mr = mf + (size_t)row*HH;
      float mreg[16];
#pragma unroll
      for (int k = 0; k < 16; ++k) mreg[k] = (float)mr[ln + 64*k];
      for (int a = 0; a < AA; ++a) {
        float p = 0.f;
#pragma unroll
        for (int k = 0; k < 16; ++k) p += mreg[k] * out_w[(size_t)a*HH + ln + 64*k];
        p = wred_sum(p);
        if (ln == 0) out[(size_t)row*AA + a] = p + out_b[a];
      }
    }
  }
}

// ---------------- host launch ----------------
extern "C" void kernel_launch(void* const* d_in, const int* in_sizes, int n_in,
                              void* d_out, int out_size, void* d_ws, size_t ws_size,
                              hipStream_t stream) {
  (void)in_sizes; (void)n_in; (void)out_size; (void)ws_size;
  const float* state    = (const float*)d_in[0];
  const float* demo     = (const float*)d_in[1];
  const int*   demlen   = (const int*)d_in[2];
  const float* h0       = (const float*)d_in[3];
  const float* c0       = (const float*)d_in[4];
  const float* enc_wih  = (const float*)d_in[5];
  const float* enc_whh  = (const float*)d_in[6];
  const float* enc_bih  = (const float*)d_in[7];
  const float* enc_bhh  = (const float*)d_in[8];
  const float* attn_w   = (const float*)d_in[9];
  const float* comb_w   = (const float*)d_in[11];
  const float* comb_b   = (const float*)d_in[12];
  const float* lstm_wih = (const float*)d_in[13];
  const float* lstm_whh = (const float*)d_in[14];
  const float* lstm_bih = (const float*)d_in[15];
  const float* lstm_bhh = (const float*)d_in[16];
  const float* mid_w    = (const float*)d_in[17];
  const float* mid_b    = (const float*)d_in[18];
  const float* out_w    = (const float*)d_in[19];
  const float* out_b    = (const float*)d_in[20];
  char* ws = (char*)d_ws;

  __bf16* wEnc  = (__bf16*)(ws + OFF_WENC);
  __bf16* wLstm = (__bf16*)(ws + OFF_WLSTM);
  __bf16* wComb = (__bf16*)(ws + OFF_WCOMB);
  __bf16* wMid  = (__bf16*)(ws + OFF_WMID);
  float*  bE    = (float*)(ws + OFF_BIASE);
  float*  bL    = (float*)(ws + OFF_BIASL);
  __bf16* demoC = (__bf16*)(ws + OFF_DEMO);
  __bf16* stateB= (__bf16*)(ws + OFF_STATE);
  __bf16* encB  = (__bf16*)(ws + OFF_ENC);
  __bf16* hdec  = (__bf16*)(ws + OFF_HDEC);
  __bf16* xall  = (__bf16*)(ws + OFF_XALL);
  __bf16* mf    = (__bf16*)(ws + OFF_MF);
  __bf16* attnS = (__bf16*)(ws + OFF_ATTNS);
  __bf16* hrotE = (__bf16*)(ws + OFF_HROT);
  __bf16* hrotD = hrotE + (size_t)GROUPS*NSLOT_E*8*HH;
  unsigned* flagsE = (unsigned*)(ws + OFF_BAR);
  unsigned* flagsD = flagsE + (size_t)NBLK*FLAG_STRIDE;
  float*  out   = (float*)d_out;

  k_prep<<<PGRID, 256, 0, stream>>>(enc_wih, enc_whh, enc_bih, enc_bhh,
                                    lstm_wih, lstm_whh, lstm_bih, lstm_bhh,
                                    comb_w, mid_w, demo, state, ws);
  k_enc<<<NBLK, 256, 0, stream>>>(demoC, wEnc, bE, hrotE, encB, flagsE);
  k_attn<<<256, 256, 0, stream>>>(demlen, h0, attn_w, encB, attnS, hrotD);
  k_x<<<256, 256, 0, stream>>>(attnS, stateB, wComb, comb_b, xall);
  k_dec<<<NBLK, 256, 0, stream>>>(xall, wLstm, bL, c0, hrotD, hdec, out, flagsD);
  k_mid<<<256, 256, 0, stream>>>(hdec, wMid, mid_b, mf);
  k_out<<<256, 256, 0, stream>>>(mf, out_w, out_b, out);
}